// Round 9
// baseline (264.669 us; speedup 1.0000x reference)
//
#include <hip/hip_runtime.h>
#include <math.h>

#define S_   2048
#define D_   1024
#define H_   16
#define HD_  64
#define BH_  64
#define TOK_ 8192

typedef __attribute__((ext_vector_type(8))) short  short8;
typedef __attribute__((ext_vector_type(4))) float  floatx4;

__device__ __forceinline__ short f2bf(float f) {
  union { float f; unsigned u; } c; c.f = f;
  unsigned u = c.u;
  u += 0x7fffu + ((u >> 16) & 1u);   // RNE
  return (short)(u >> 16);
}

__device__ __forceinline__ float max3f(float a, float b, float c) {
  float d; asm("v_max3_f32 %0, %1, %2, %3" : "=v"(d) : "v"(a), "v"(b), "v"(c)); return d;
}

__device__ __forceinline__ void gload16(const void* g, void* l) {
  __builtin_amdgcn_global_load_lds((const __attribute__((address_space(1))) void*)g,
                                   (__attribute__((address_space(3))) void*)l, 16, 0, 0);
}

// ---------------- fp32 -> bf16 elementwise (x) ----------------
__global__ void cvt_x_kernel(const float* __restrict__ in, short* __restrict__ out, int n8) {
  int i = blockIdx.x * blockDim.x + threadIdx.x;
  if (i >= n8) return;
  const float4* p = (const float4*)in;
  float4 a = p[i * 2], b = p[i * 2 + 1];
  short8 o;
  o[0] = f2bf(a.x); o[1] = f2bf(a.y); o[2] = f2bf(a.z); o[3] = f2bf(a.w);
  o[4] = f2bf(b.x); o[5] = f2bf(b.y); o[6] = f2bf(b.z); o[7] = f2bf(b.w);
  ((short8*)out)[i] = o;
}

// ---------------- W [R][C] fp32 -> Wt [C][R] bf16 ----------------
__global__ void tconv_kernel(const float* __restrict__ in, short* __restrict__ out, int R, int C) {
  __shared__ float t[32][33];
  int tx = threadIdx.x, ty = threadIdx.y;
  int c0 = blockIdx.x * 32, r0 = blockIdx.y * 32;
#pragma unroll
  for (int i = 0; i < 4; ++i)
    t[ty + i * 8][tx] = in[(r0 + ty + i * 8) * C + c0 + tx];
  __syncthreads();
#pragma unroll
  for (int i = 0; i < 4; ++i)
    out[(c0 + ty + i * 8) * R + r0 + tx] = f2bf(t[tx][ty + i * 8]);
}

// ---------------- GEMM1: qkv = x @ Wqkv, scatter q/k -> [bh][s][d], v -> vt [bh][d][s] ----
// q is pre-scaled by (1/sqrt(hd))*log2(e) so attn uses exp2. V-transpose fused here.
__global__ __launch_bounds__(256) void gemm_qkv_kernel(
    const short* __restrict__ A, const short* __restrict__ Bt,
    short* __restrict__ qb, short* __restrict__ kb, short* __restrict__ vtb) {
  __shared__ short sA[128 * 32];
  __shared__ short sB[128 * 32];
  const int tid = threadIdx.x;
  const int lane = tid & 63, wid = tid >> 6;
  const int wm = wid >> 1, wn = wid & 1;
  const int lr = lane & 15, lg = lane >> 4;
  const int m0 = blockIdx.x * 128, n0 = blockIdx.y * 128;
  floatx4 acc[4][4] = {};
  const int f1 = tid * 16;
  const int rS1 = f1 >> 6, cS1 = (f1 & 63) >> 1;
  const int f2 = f1 + 4096;
  const int rS2 = f2 >> 6, cS2 = (f2 & 63) >> 1;
  for (int kt = 0; kt < 32; ++kt) {
    const int k0 = kt * 32;
    __syncthreads();
    gload16(&A[(m0 + rS1) * 1024 + k0 + cS1], (char*)sA + f1);
    gload16(&A[(m0 + rS2) * 1024 + k0 + cS2], (char*)sA + f2);
    gload16(&Bt[(n0 + rS1) * 1024 + k0 + cS1], (char*)sB + f1);
    gload16(&Bt[(n0 + rS2) * 1024 + k0 + cS2], (char*)sB + f2);
    __syncthreads();
    short8 af[4], bfv[4];
#pragma unroll
    for (int mf = 0; mf < 4; ++mf)
      af[mf] = *(const short8*)&sA[(wm * 64 + mf * 16 + lr) * 32 + lg * 8];
#pragma unroll
    for (int nf = 0; nf < 4; ++nf)
      bfv[nf] = *(const short8*)&sB[(wn * 64 + nf * 16 + lr) * 32 + lg * 8];
#pragma unroll
    for (int mf = 0; mf < 4; ++mf)
#pragma unroll
      for (int nf = 0; nf < 4; ++nf)
        acc[mf][nf] = __builtin_amdgcn_mfma_f32_16x16x32_bf16(af[mf], bfv[nf], acc[mf][nf], 0, 0, 0);
  }
  const int sec = n0 >> 10;  // 0=q 1=k 2=v (128 | 1024 so uniform per block)
  if (sec < 2) {
    short* dst = sec == 0 ? qb : kb;
    const float scale = (sec == 0) ? 0.18033688011112042f : 1.0f;
#pragma unroll
    for (int mf = 0; mf < 4; ++mf) {
#pragma unroll
      for (int nf = 0; nf < 4; ++nf) {
        const int col = n0 + wn * 64 + nf * 16 + lr;
        const int w = col & 1023;
        const int h = w >> 6, d = w & 63;
#pragma unroll
        for (int r = 0; r < 4; ++r) {
          const int token = m0 + wm * 64 + mf * 16 + lg * 4 + r;
          const int b = token >> 11, s = token & 2047;
          dst[(((b << 4) | h) * 2048 + s) * 64 + d] = f2bf(acc[mf][nf][r] * scale);
        }
      }
    }
  } else {
    // v: write transposed [bh][d][s], 4 consecutive tokens packed per 8B store
#pragma unroll
    for (int mf = 0; mf < 4; ++mf) {
      const int token0 = m0 + wm * 64 + mf * 16 + lg * 4;
      const int bb = token0 >> 11, s0v = token0 & 2047;
#pragma unroll
      for (int nf = 0; nf < 4; ++nf) {
        const int col = n0 + wn * 64 + nf * 16 + lr;
        const int w = col & 1023;
        const int h = w >> 6, d = w & 63;
        union { unsigned long long u; short s[4]; } pk;
        pk.s[0] = f2bf(acc[mf][nf][0]);
        pk.s[1] = f2bf(acc[mf][nf][1]);
        pk.s[2] = f2bf(acc[mf][nf][2]);
        pk.s[3] = f2bf(acc[mf][nf][3]);
        *(unsigned long long*)&vtb[((((bb << 4) | h) * 64 + d) << 11) + s0v] = pk.u;
      }
    }
  }
}

// ---------------- GEMM2: out = att @ Wproj + bias (fp32 out) ----------------
__global__ __launch_bounds__(256) void gemm_proj_kernel(
    const short* __restrict__ A, const short* __restrict__ Bt,
    const float* __restrict__ bias, float* __restrict__ out) {
  __shared__ short sA[128 * 32];
  __shared__ short sB[128 * 32];
  const int tid = threadIdx.x;
  const int lane = tid & 63, wid = tid >> 6;
  const int wm = wid >> 1, wn = wid & 1;
  const int lr = lane & 15, lg = lane >> 4;
  const int m0 = blockIdx.x * 128, n0 = blockIdx.y * 128;
  floatx4 acc[4][4] = {};
  const int f1 = tid * 16;
  const int rS1 = f1 >> 6, cS1 = (f1 & 63) >> 1;
  const int f2 = f1 + 4096;
  const int rS2 = f2 >> 6, cS2 = (f2 & 63) >> 1;
  for (int kt = 0; kt < 32; ++kt) {
    const int k0 = kt * 32;
    __syncthreads();
    gload16(&A[(m0 + rS1) * 1024 + k0 + cS1], (char*)sA + f1);
    gload16(&A[(m0 + rS2) * 1024 + k0 + cS2], (char*)sA + f2);
    gload16(&Bt[(n0 + rS1) * 1024 + k0 + cS1], (char*)sB + f1);
    gload16(&Bt[(n0 + rS2) * 1024 + k0 + cS2], (char*)sB + f2);
    __syncthreads();
    short8 af[4], bfv[4];
#pragma unroll
    for (int mf = 0; mf < 4; ++mf)
      af[mf] = *(const short8*)&sA[(wm * 64 + mf * 16 + lr) * 32 + lg * 8];
#pragma unroll
    for (int nf = 0; nf < 4; ++nf)
      bfv[nf] = *(const short8*)&sB[(wn * 64 + nf * 16 + lr) * 32 + lg * 8];
#pragma unroll
    for (int mf = 0; mf < 4; ++mf)
#pragma unroll
      for (int nf = 0; nf < 4; ++nf)
        acc[mf][nf] = __builtin_amdgcn_mfma_f32_16x16x32_bf16(af[mf], bfv[nf], acc[mf][nf], 0, 0, 0);
  }
#pragma unroll
  for (int mf = 0; mf < 4; ++mf) {
#pragma unroll
    for (int nf = 0; nf < 4; ++nf) {
      const int col = n0 + wn * 64 + nf * 16 + lr;
      const float bv = bias[col];
#pragma unroll
      for (int r = 0; r < 4; ++r) {
        const int row = m0 + wm * 64 + mf * 16 + lg * 4 + r;
        out[row * 1024 + col] = acc[mf][nf][r] + bv;
      }
    }
  }
}

// ---------------- Flash attention (causal), bf16 in/out ----------------
// v5: v4 + 3-buffer K/VT rotation with counted vmcnt(4) (T4: never drain in
// steady state; stage t+2 issued after the iter-t barrier -> race-free since
// buffer (t+2)%3 was last read in iter t-1, completed before that barrier),
// running stage pointers, v_max3 row-max. One s_barrier per tile.
__global__ __launch_bounds__(256) void attn_kernel(
    const short* __restrict__ qb, const short* __restrict__ kb,
    const short* __restrict__ vtb, short* __restrict__ attb) {
  __shared__ short sK[3][64 * 64];
  __shared__ short sVT[3][64 * 64];
  __shared__ short sP[4][32 * 64];
  const int tid = threadIdx.x;
  const int lane = tid & 63, wid = tid >> 6;
  const int lr = lane & 15, lg = lane >> 4;

  // XCD swizzle: each XCD's 64 blocks cover 8 consecutive bh (K/V in its L2).
  const int bid = blockIdx.x;                 // 0..511
  const int wgid = (bid & 7) * 64 + (bid >> 3);
  const int bh = wgid >> 3;                   // 0..63
  const int qx = wgid & 7;                    // 0..7

  const char* kbase = (const char*)(kb + bh * S_ * HD_);
  const char* vtbase = (const char*)(vtb + bh * HD_ * S_);
  const short* qbase = qb + bh * S_ * HD_;
  char* pbase = (char*)&sP[wid][0];
  const int b = bh >> 4, h = bh & 15;

  const int f1 = tid * 16;
  const int ro1 = f1 >> 7, cb1 = f1 & 127;
  const int sc1 = cb1 ^ ((ro1 & 7) << 4);
  const int f2 = f1 + 4096;
  const int ro2 = f2 >> 7, cb2 = f2 & 127;
  const int sc2 = cb2 ^ ((ro2 & 7) << 4);

  const int swz = (lr & 7) << 4;

  short8 vones;
#pragma unroll
  for (int j = 0; j < 8; ++j) vones[j] = (short)0x3F80;  // bf16 1.0

#pragma unroll 1
  for (int half = 0; half < 2; ++half) {
    const int qt = half ? (15 - qx) : qx;
    const int qw = qt * 128 + wid * 32;

    short8 qf[2][2];
#pragma unroll
    for (int qtile = 0; qtile < 2; ++qtile)
#pragma unroll
      for (int kf = 0; kf < 2; ++kf)
        qf[qtile][kf] = *(const short8*)&qbase[(qw + qtile * 16 + lr) * 64 + kf * 32 + lg * 8];

    floatx4 acc_o[2][4] = {};
    floatx4 acc_den[2] = {};
    float mrun[2] = {-1e30f, -1e30f};

    const int ntiles = 2 * qt + 2;   // >= 2

    // all waves done reading previous half's buffers before restaging
    __builtin_amdgcn_s_barrier();

    const char* kp1 = kbase + ro1 * 128 + sc1;
    const char* kp2 = kbase + ro2 * 128 + sc2;
    const char* vp1 = vtbase + ro1 * 4096 + sc1;
    const char* vp2 = vtbase + ro2 * 4096 + sc2;

    // prologue: stage tiles 0 and 1 into bufs 0 and 1
    gload16(kp1, (char*)sK[0] + f1);  gload16(kp2, (char*)sK[0] + f2);
    gload16(vp1, (char*)sVT[0] + f1); gload16(vp2, (char*)sVT[0] + f2);
    kp1 += 8192; kp2 += 8192; vp1 += 128; vp2 += 128;
    gload16(kp1, (char*)sK[1] + f1);  gload16(kp2, (char*)sK[1] + f2);
    gload16(vp1, (char*)sVT[1] + f1); gload16(vp2, (char*)sVT[1] + f2);
    kp1 += 8192; kp2 += 8192; vp1 += 128; vp2 += 128;

    int cur = 0, nxt2 = 2;
#pragma unroll 1
    for (int t = 0; t < ntiles; ++t) {
      if (t < ntiles - 1) { asm volatile("s_waitcnt vmcnt(4)" ::: "memory"); }
      else                { asm volatile("s_waitcnt vmcnt(0)" ::: "memory"); }
      __builtin_amdgcn_s_barrier();
      __builtin_amdgcn_sched_barrier(0);
      // stage tile t+2 into the buffer last read in iter t-1 (safe past barrier)
      if (t + 2 < ntiles) {
        char* dK = (char*)sK[nxt2];
        char* dV = (char*)sVT[nxt2];
        gload16(kp1, dK + f1);  gload16(kp2, dK + f2);
        gload16(vp1, dV + f1);  gload16(vp2, dV + f2);
      }
      kp1 += 8192; kp2 += 8192; vp1 += 128; vp2 += 128;

      const int key0 = t * 64;
      if (key0 <= qw + 31) {  // wave-uniform: skip fully-masked tiles
        const char* cK = (const char*)sK[cur];
        const char* cV = (const char*)sVT[cur];

        // S^T = K Q^T : lane holds keys kt*16+lg*4+{0..3} of q-row (qtile*16+lr)
        floatx4 sT[4][2] = {};
        __builtin_amdgcn_s_setprio(1);
#pragma unroll
        for (int kt = 0; kt < 4; ++kt) {
#pragma unroll
          for (int kf = 0; kf < 2; ++kf) {
            short8 kfrag = *(const short8*)(cK + (kt * 16 + lr) * 128 + ((kf * 64 + lg * 16) ^ swz));
#pragma unroll
            for (int qtile = 0; qtile < 2; ++qtile)
              sT[kt][qtile] = __builtin_amdgcn_mfma_f32_16x16x32_bf16(kfrag, qf[qtile][kf], sT[kt][qtile], 0, 0, 0);
          }
        }
        __builtin_amdgcn_s_setprio(0);

        if (key0 + 63 > qw) {  // wave-uniform: diagonal tile, apply causal mask
#pragma unroll
          for (int kt = 0; kt < 4; ++kt)
#pragma unroll
            for (int qtile = 0; qtile < 2; ++qtile)
#pragma unroll
              for (int r = 0; r < 4; ++r)
                if (key0 + kt * 16 + lg * 4 + r > qw + qtile * 16 + lr) sT[kt][qtile][r] = -1e30f;
        }

        // per-q-row max: in-lane (max3 tree) + butterfly across lg groups
        float mx[2], al[2];
        bool need = false;
#pragma unroll
        for (int qtile = 0; qtile < 2; ++qtile) {
          float m = max3f(sT[0][qtile][0], sT[0][qtile][1], sT[0][qtile][2]);
          m = max3f(m, sT[0][qtile][3], sT[1][qtile][0]);
          m = max3f(m, sT[1][qtile][1], sT[1][qtile][2]);
          m = max3f(m, sT[1][qtile][3], sT[2][qtile][0]);
          m = max3f(m, sT[2][qtile][1], sT[2][qtile][2]);
          m = max3f(m, sT[2][qtile][3], sT[3][qtile][0]);
          m = max3f(m, sT[3][qtile][1], sT[3][qtile][2]);
          m = fmaxf(m, sT[3][qtile][3]);
          m = fmaxf(m, __shfl_xor(m, 16));
          m = fmaxf(m, __shfl_xor(m, 32));
          mx[qtile] = m;
          need = need || (m > mrun[qtile] + 8.f);
        }
        if (__any(need)) {
#pragma unroll
          for (int qtile = 0; qtile < 2; ++qtile) {
            const float mnew = fmaxf(mrun[qtile], mx[qtile]);
            al[qtile] = __builtin_amdgcn_exp2f(mrun[qtile] - mnew);
            mrun[qtile] = mnew;
          }
          // broadcast alpha to O-orientation lanes
#pragma unroll
          for (int mf = 0; mf < 2; ++mf) {
#pragma unroll
            for (int r = 0; r < 4; ++r) {
              const float alr = __shfl(al[mf], lg * 4 + r);
              acc_den[mf][r] *= alr;
#pragma unroll
              for (int nfd = 0; nfd < 4; ++nfd) acc_o[mf][nfd][r] *= alr;
            }
          }
        }

        // P = exp2(S - m) -> packed bf16 pairs -> ds_write_b64
#pragma unroll
        for (int kt = 0; kt < 4; ++kt) {
#pragma unroll
          for (int qtile = 0; qtile < 2; ++qtile) {
            const float p0 = __builtin_amdgcn_exp2f(sT[kt][qtile][0] - mrun[qtile]);
            const float p1 = __builtin_amdgcn_exp2f(sT[kt][qtile][1] - mrun[qtile]);
            const float p2 = __builtin_amdgcn_exp2f(sT[kt][qtile][2] - mrun[qtile]);
            const float p3 = __builtin_amdgcn_exp2f(sT[kt][qtile][3] - mrun[qtile]);
            unsigned lo, hi;
            asm("v_cvt_pk_bf16_f32 %0, %1, %2" : "=v"(lo) : "v"(p0), "v"(p1));
            asm("v_cvt_pk_bf16_f32 %0, %1, %2" : "=v"(hi) : "v"(p2), "v"(p3));
            *(unsigned long long*)(pbase + (qtile * 16 + lr) * 128 + ((kt * 32 + lg * 8) ^ swz)) =
                ((unsigned long long)hi << 32) | lo;
          }
        }

        // O += P @ V ; den += P @ 1
        __builtin_amdgcn_s_setprio(1);
#pragma unroll
        for (int kf2 = 0; kf2 < 2; ++kf2) {
          short8 pf[2];
#pragma unroll
          for (int mf = 0; mf < 2; ++mf) {
            pf[mf] = *(const short8*)(pbase + (mf * 16 + lr) * 128 + ((kf2 * 64 + lg * 16) ^ swz));
            acc_den[mf] = __builtin_amdgcn_mfma_f32_16x16x32_bf16(pf[mf], vones, acc_den[mf], 0, 0, 0);
          }
#pragma unroll
          for (int nfd = 0; nfd < 4; ++nfd) {
            short8 vfrag = *(const short8*)(cV + (nfd * 16 + lr) * 128 + ((kf2 * 64 + lg * 16) ^ swz));
#pragma unroll
            for (int mf = 0; mf < 2; ++mf)
              acc_o[mf][nfd] = __builtin_amdgcn_mfma_f32_16x16x32_bf16(pf[mf], vfrag, acc_o[mf][nfd], 0, 0, 0);
          }
        }
        __builtin_amdgcn_s_setprio(0);
      }

      cur = (cur == 2) ? 0 : cur + 1;
      nxt2 = (nxt2 == 2) ? 0 : nxt2 + 1;
    }

    // epilogue -> att [token][h*64+d] bf16
#pragma unroll
    for (int mf = 0; mf < 2; ++mf) {
#pragma unroll
      for (int nfd = 0; nfd < 4; ++nfd) {
#pragma unroll
        for (int r = 0; r < 4; ++r) {
          const float o = acc_o[mf][nfd][r] / acc_den[mf][r];
          const int qrow = qw + mf * 16 + lg * 4 + r;
          const int d = nfd * 16 + lr;
          attb[(b * 2048 + qrow) * 1024 + h * 64 + d] = f2bf(o);
        }
      }
    }
  }
}

extern "C" void kernel_launch(void* const* d_in, const int* in_sizes, int n_in,
                              void* d_out, int out_size, void* d_ws, size_t ws_size,
                              hipStream_t stream) {
  (void)in_sizes; (void)n_in; (void)out_size; (void)ws_size;
  const float* x = (const float*)d_in[0];
  const float* Wqkv = (const float*)d_in[1];
  const float* Wproj = (const float*)d_in[2];
  const float* bproj = (const float*)d_in[3];
  float* out = (float*)d_out;

  char* w = (char*)d_ws;
  short* xb     = (short*)(w + 0);          // 16 MiB  [8192][1024]
  short* wqkvT  = (short*)(w + 16777216);   // 6 MiB   [3072][1024]
  short* wprojT = (short*)(w + 23068672);   // 2 MiB   [1024][1024]
  short* qb     = (short*)(w + 25165824);   // 16 MiB  [bh][s][d]
  short* kb     = (short*)(w + 41943040);   // 16 MiB
  short* vtb    = (short*)(w + 75497472);   // 16 MiB  [bh][d][s] (written by gemm_qkv)
  short* attb   = (short*)(w + 92274688);   // 16 MiB  [8192][1024]

  cvt_x_kernel<<<4096, 256, 0, stream>>>(x, xb, TOK_ * D_ / 8);
  tconv_kernel<<<dim3(96, 32), dim3(32, 8), 0, stream>>>(Wqkv, wqkvT, 1024, 3072);
  tconv_kernel<<<dim3(32, 32), dim3(32, 8), 0, stream>>>(Wproj, wprojT, 1024, 1024);
  gemm_qkv_kernel<<<dim3(64, 24), 256, 0, stream>>>(xb, wqkvT, qb, kb, vtb);
  attn_kernel<<<512, 256, 0, stream>>>(qb, kb, vtb, attb);
  gemm_proj_kernel<<<dim3(64, 8), 256, 0, stream>>>(attb, wprojT, bproj, out);
}